// Round 4
// baseline (148.313 us; speedup 1.0000x reference)
//
#include <hip/hip_runtime.h>
#include <hip/hip_fp16.h>
#include <cstdint>

// Problem constants (B,H,S,D from reference setup_inputs; KP = int(S*0.1))
#define BB 2
#define HH 12
#define SS 1024
#define DD 64
#define KP 102
#define QPB 4     // queries per block in select (1 wave each)

typedef _Float16 half2v __attribute__((ext_vector_type(2)));
typedef _Float16 half8v __attribute__((ext_vector_type(8)));
typedef float    f32x4  __attribute__((ext_vector_type(4)));

// popcount of (m & lanes_below_me) in 2 VALU insts
__device__ __forceinline__ int mbcnt64(unsigned long long m) {
    return (int)__builtin_amdgcn_mbcnt_hi((unsigned)(m >> 32),
               __builtin_amdgcn_mbcnt_lo((unsigned)(m & 0xffffffffull), 0u));
}

// ---------------------------------------------------------------------------
// Kernel 1 (PACK): kbits = sign mask of k rows; kh = f16(k * 0.125)
// (softmax scale 1/sqrt(64) folded into K; exact power-of-2, no precision loss)
// ---------------------------------------------------------------------------
__global__ __launch_bounds__(256) void pack_kernel(
    const float* __restrict__ k,
    unsigned long long* __restrict__ kbits, _Float16* __restrict__ kh)
{
    int row  = (int)((blockIdx.x * 256 + threadIdx.x) >> 6);
    int lane = (int)(threadIdx.x & 63);
    if (row >= BB * HH * SS) return;
    float kv = k[(size_t)row * DD + lane];
    unsigned long long km = __ballot(kv > 0.0f);
    kh[(size_t)row * DD + lane] = (_Float16)(kv * 0.125f);
    if (lane == 0) kbits[row] = km;
}

// ---------------------------------------------------------------------------
// Kernel 2 (TRANSPOSE): vT[bh][dim][key] f16 from v[bh][key][dim] f32.
// One block per 64-key chunk; LDS-staged, both sides coalesced.
// ---------------------------------------------------------------------------
__global__ __launch_bounds__(256) void vtrans_kernel(
    const float* __restrict__ v, _Float16* __restrict__ vT)
{
    __shared__ _Float16 lds[64][66];          // +2 pad: conflict-free col reads
    const int t = (int)threadIdx.x;
    const int kb64 = (int)blockIdx.x * 64;    // global key-row base
    const int bh = kb64 >> 10;
    const int keybase = kb64 & (SS - 1);
    #pragma unroll
    for (int e = 0; e < 16; ++e) {
        int key = e * 4 + (t >> 6);
        int dim = t & 63;
        lds[key][dim] = (_Float16)v[((size_t)kb64 + key) * DD + dim];
    }
    __syncthreads();
    #pragma unroll
    for (int e = 0; e < 16; ++e) {
        int dim = e * 4 + (t >> 6);
        int key = t & 63;
        vT[((size_t)bh * DD + dim) * SS + keybase + key] = lds[key][dim];
    }
}

// ---------------------------------------------------------------------------
// Kernel 3 (SELECT): phases A/B as before; phase C now writes the per-query
// take-masks directly: selmask[query][j] (u64, bit i = key j*64+i selected).
// Selection set identical to prior rounds (ties index-ascending).
// ---------------------------------------------------------------------------
__global__ __launch_bounds__(256, 4) void select_kernel(
    const float* __restrict__ q,
    const unsigned long long* __restrict__ kbits,
    unsigned long long* __restrict__ selmask)
{
    const int tid  = (int)threadIdx.x;
    const int w    = tid >> 6;
    const int lane = tid & 63;
    const int query = (int)blockIdx.x * QPB + w;
    const int bh    = query >> 10;

    const float qreg = q[(size_t)query * DD + lane];
    const unsigned long long qm = __ballot(qreg > 0.0f);

    const unsigned long long* kb = kbits + (size_t)bh * SS;
    int pbin[16];
    #pragma unroll
    for (int j = 0; j < 16; ++j)
        pbin[j] = (int)__popcll(qm ^ kb[j * 64 + lane]);

    #define COUNT_LE(P, OUTC)                                      \
        { int _c = 0;                                              \
          _Pragma("unroll")                                        \
          for (int j = 0; j < 16; ++j)                             \
              _c += (int)__popcll(__ballot(pbin[j] <= (P)));       \
          (OUTC) = _c; }
    int P = 27, c, clt;
    COUNT_LE(P, c);
    if (c >= KP) {
        COUNT_LE(P - 1, clt);
        while (clt >= KP) { c = clt; --P; COUNT_LE(P - 1, clt); }
    } else {
        do { clt = c; ++P; COUNT_LE(P, c); } while (c < KP);
    }
    const int binP = P;
    const int need = KP - clt;
    #undef COUNT_LE

    unsigned long long* selq = selmask + (size_t)query * 16;
    int tie_base = 0;
    #pragma unroll
    for (int j = 0; j < 16; ++j) {
        bool isGt  = pbin[j] < binP;
        bool isTie = (pbin[j] == binP);
        unsigned long long tiem = __ballot(isTie);
        int rank = tie_base + mbcnt64(tiem);
        bool take = isGt || (isTie && rank < need);
        unsigned long long tm = __ballot(take);
        if (lane == 0) selq[j] = tm;
        tie_base += (int)__popcll(tiem);
    }
}

// ---------------------------------------------------------------------------
// Kernel 4 (ATTN): dense MFMA attention with selection mask.
// Block = 256 thr = 4 waves sharing 16 Q-rows; wave w owns key quarter
// [w*256, w*256+256). Per 32-key chunk: T = K_tile . Q^T via 4 MFMA
// (T[m=key][n=qrow]); e = selbit ? exp(s+mask) : 0 on VALU/trans pipes;
// P^T staged in wave-private LDS; out^T += V^T_tile . P^T via 4 MFMA.
// Unnormalized O,l partials from the 4 key-quarters add exactly (no
// max-subtraction; s bounded ~|8|, f32 exp). Merge via LDS + one barrier.
// Fragment layouts per m89/m91/m97-verified pattern:
//   A/B frag: 8 contiguous-k f16 at row (lane&15), k-block (lane>>4)
//   C/D frag: col = lane&15, row = (lane>>4)*4 + j
// ---------------------------------------------------------------------------
__global__ __launch_bounds__(256, 4) void attn_kernel(
    const float* __restrict__ q, const _Float16* __restrict__ kh,
    const _Float16* __restrict__ vT, const float* __restrict__ mask,
    const unsigned long long* __restrict__ selmask,
    float* __restrict__ out)
{
    const int tid  = (int)threadIdx.x;
    const int w    = tid >> 6;                 // key-quarter
    const int lane = tid & 63;
    const int r    = lane & 15;                // frag row/col index
    const int g    = lane >> 4;                // frag k-group
    const int qbase = (int)blockIdx.x * 16;
    const int bh = qbase >> 10;
    const int b  = bh / HH;
    const int query = qbase + r;

    __shared__ _Float16 pbuf[4][16][40];       // wave-private P^T stage (pad 40)
    __shared__ float    mbuf[4][64][17];       // merge: 16 O regs + l per lane

    // Q B-frags (unscaled f16; scale folded into kh)
    half8v qf[2];
    #pragma unroll
    for (int mb = 0; mb < 2; ++mb) {
        const float* qp = q + (size_t)query * DD + mb * 32 + g * 8;
        float4 f0 = *(const float4*)qp;
        float4 f1 = *(const float4*)(qp + 4);
        half8v h;
        h[0] = (_Float16)f0.x; h[1] = (_Float16)f0.y;
        h[2] = (_Float16)f0.z; h[3] = (_Float16)f0.w;
        h[4] = (_Float16)f1.x; h[5] = (_Float16)f1.y;
        h[6] = (_Float16)f1.z; h[7] = (_Float16)f1.w;
        qf[mb] = h;
    }

    // this lane's row-mask for this wave's key quarter: 4 u64 = 8 dwords.
    // dword kc covers keys w*256 + kc*32 .. +31 (bit = local key index).
    const unsigned* selp = (const unsigned*)(selmask + (size_t)query * 16 + w * 4);
    uint4 sm0 = *(const uint4*)selp;
    uint4 sm1 = *(const uint4*)(selp + 4);
    unsigned smw[8] = {sm0.x, sm0.y, sm0.z, sm0.w, sm1.x, sm1.y, sm1.z, sm1.w};

    const _Float16* khb   = kh + ((size_t)bh * SS + w * 256) * DD;
    const _Float16* vTb   = vT + (size_t)bh * DD * SS + w * 256;
    const float*    maskb = mask + (size_t)b * SS + w * 256;

    f32x4 oacc[4];
    #pragma unroll
    for (int db = 0; db < 4; ++db) oacc[db] = (f32x4){0.f, 0.f, 0.f, 0.f};
    float l_part = 0.0f;
    const int g4 = g * 4, g8 = g * 8;

    #pragma unroll
    for (int kc = 0; kc < 8; ++kc) {
        // ---- QK^T: two 16-key T-tiles (K=64 over 2 MFMAs each) ----
        f32x4 ct[2];
        #pragma unroll
        for (int tt = 0; tt < 2; ++tt) {
            const _Float16* kp = khb + (size_t)(kc * 32 + tt * 16 + r) * DD + g8;
            half8v ka0 = *(const half8v*)kp;          // dims g8..g8+7
            half8v ka1 = *(const half8v*)(kp + 32);   // dims 32+g8..
            f32x4 cacc = (f32x4){0.f, 0.f, 0.f, 0.f};
            cacc = __builtin_amdgcn_mfma_f32_16x16x32_f16(ka0, qf[0], cacc, 0, 0, 0);
            cacc = __builtin_amdgcn_mfma_f32_16x16x32_f16(ka1, qf[1], cacc, 0, 0, 0);
            ct[tt] = cacc;
        }
        // ---- mask + select + exp -> P^T (f16) in LDS ----
        const unsigned sw = smw[kc];
        #pragma unroll
        for (int tt = 0; tt < 2; ++tt) {
            float4 mv = *(const float4*)(maskb + kc * 32 + tt * 16 + g4);
            float mvj[4] = {mv.x, mv.y, mv.z, mv.w};
            float e[4];
            #pragma unroll
            for (int j = 0; j < 4; ++j) {
                float s  = ct[tt][j] + mvj[j];
                float ev = __expf(s);
                unsigned bit = (sw >> (tt * 16 + g4 + j)) & 1u;
                ev = bit ? ev : 0.0f;
                e[j] = ev;
                l_part += ev;
            }
            half2v p0; p0[0] = (_Float16)e[0]; p0[1] = (_Float16)e[1];
            half2v p1; p1[0] = (_Float16)e[2]; p1[1] = (_Float16)e[3];
            *(half2v*)&pbuf[w][r][tt * 16 + g4]     = p0;
            *(half2v*)&pbuf[w][r][tt * 16 + g4 + 2] = p1;
        }
        // ---- PV: out^T += V^T_tile . P^T ----
        half8v pf = *(const half8v*)&pbuf[w][r][g8];   // B-frag: row r, keys g8..g8+7
        #pragma unroll
        for (int db = 0; db < 4; ++db) {
            const _Float16* vp = vTb + (size_t)(db * 16 + r) * SS + kc * 32 + g8;
            half8v va = *(const half8v*)vp;
            oacc[db] = __builtin_amdgcn_mfma_f32_16x16x32_f16(va, pf, oacc[db], 0, 0, 0);
        }
    }

    // intra-wave l reduce: sum the 4 g-groups per row
    l_part += __shfl_xor(l_part, 16);
    l_part += __shfl_xor(l_part, 32);

    // dump partials
    #pragma unroll
    for (int db = 0; db < 4; ++db)
        #pragma unroll
        for (int j = 0; j < 4; ++j)
            mbuf[w][lane][db * 4 + j] = oacc[db][j];
    mbuf[w][lane][16] = l_part;
    __syncthreads();

    // cross-wave merge: thread -> (row, gg, db); 4 output dims each
    {
        const int row = tid & 15, gg = (tid >> 4) & 3, db = tid >> 6;
        const int src = gg * 16 + row;             // lane that held (row, g=gg)
        float o0 = 0.f, o1 = 0.f, o2 = 0.f, o3 = 0.f, ls = 0.f;
        #pragma unroll
        for (int ww = 0; ww < 4; ++ww) {
            o0 += mbuf[ww][src][db * 4 + 0];
            o1 += mbuf[ww][src][db * 4 + 1];
            o2 += mbuf[ww][src][db * 4 + 2];
            o3 += mbuf[ww][src][db * 4 + 3];
            ls += mbuf[ww][src][16];
        }
        const float rinv = __frcp_rn(ls);
        float4 o = make_float4(o0 * rinv, o1 * rinv, o2 * rinv, o3 * rinv);
        *(float4*)(out + (size_t)(qbase + row) * DD + db * 16 + gg * 4) = o;
    }
}

extern "C" void kernel_launch(void* const* d_in, const int* in_sizes, int n_in,
                              void* d_out, int out_size, void* d_ws, size_t ws_size,
                              hipStream_t stream) {
    const float* q    = (const float*)d_in[0];
    const float* k    = (const float*)d_in[1];
    const float* v    = (const float*)d_in[2];
    const float* mask = (const float*)d_in[3];
    float* out = (float*)d_out;

    const int rows = BB * HH * SS;                 // 24576
    char* ws = (char*)d_ws;
    unsigned long long* kbits = (unsigned long long*)ws;            // 196608 B
    _Float16* kh = (_Float16*)(ws + (size_t)rows * 8);              // 3145728 B
    _Float16* vT = (_Float16*)(ws + (size_t)rows * 8
                                  + (size_t)rows * DD * 2);         // 3145728 B
    unsigned long long* selmask = (unsigned long long*)(ws + (size_t)rows * 8
                                  + 2 * (size_t)rows * DD * 2);     // 3145728 B

    pack_kernel<<<(rows * 64 + 255) / 256, 256, 0, stream>>>(k, kbits, kh);
    vtrans_kernel<<<rows / 64, 256, 0, stream>>>(v, vT);
    select_kernel<<<rows / QPB, 256, 0, stream>>>(q, kbits, selmask);
    attn_kernel<<<rows / 16, 256, 0, stream>>>(q, kh, vT, mask, selmask, out);
}

// Round 5
// 122.111 us; speedup vs baseline: 1.2146x; 1.2146x over previous
//
#include <hip/hip_runtime.h>
#include <hip/hip_fp16.h>
#include <cstdint>

// Problem constants (B,H,S,D from reference setup_inputs; KP = int(S*0.1))
#define BB 2
#define HH 12
#define SS 1024
#define DD 64
#define KP 102
#define QPB 4     // queries per block in select (1 wave each)

typedef _Float16 half2v __attribute__((ext_vector_type(2)));
typedef _Float16 half8v __attribute__((ext_vector_type(8)));
typedef float    f32x4  __attribute__((ext_vector_type(4)));

// popcount of (m & lanes_below_me) in 2 VALU insts
__device__ __forceinline__ int mbcnt64(unsigned long long m) {
    return (int)__builtin_amdgcn_mbcnt_hi((unsigned)(m >> 32),
               __builtin_amdgcn_mbcnt_lo((unsigned)(m & 0xffffffffull), 0u));
}

// async global->LDS, 16B per lane. LDS dest = wave-uniform base + lane*16
// (m104); global src is per-lane. Swizzled layouts via pre-swizzled SOURCE
// (rule 21: linear dest + inverse-swz source + swz on read).
__device__ __forceinline__ void gl_lds16(const void* g, void* l) {
    __builtin_amdgcn_global_load_lds(
        (const __attribute__((address_space(1))) unsigned int*)g,
        (__attribute__((address_space(3))) unsigned int*)l,
        16, 0, 0);
}

// ---------------------------------------------------------------------------
// Kernel 1 (PREP): fuses pack (kbits sign-mask + kh = f16(k*0.125)) and the
// V transpose (vT[bh][dim][key] f16). One block per 64 key-rows.
// ---------------------------------------------------------------------------
__global__ __launch_bounds__(256) void prep_kernel(
    const float* __restrict__ k, const float* __restrict__ v,
    unsigned long long* __restrict__ kbits, _Float16* __restrict__ kh,
    _Float16* __restrict__ vT)
{
    const int t = (int)threadIdx.x, w = t >> 6, lane = t & 63;
    const int kb64 = (int)blockIdx.x * 64;
    const int bh = kb64 >> 10, keybase = kb64 & (SS - 1);

    // K: wave w handles rows w*16 .. w*16+15 (full-wave ballot per row)
    #pragma unroll
    for (int e = 0; e < 16; ++e) {
        int row = kb64 + w * 16 + e;
        float kv = k[(size_t)row * DD + lane];
        unsigned long long km = __ballot(kv > 0.0f);
        kh[(size_t)row * DD + lane] = (_Float16)(kv * 0.125f);
        if (lane == 0) kbits[row] = km;
    }

    // V transpose via LDS (both sides coalesced)
    __shared__ _Float16 lds[64][66];          // +2 pad
    #pragma unroll
    for (int e = 0; e < 16; ++e) {
        int key = e * 4 + w;
        int dim = t & 63;
        lds[key][dim] = (_Float16)v[((size_t)kb64 + key) * DD + dim];
    }
    __syncthreads();
    #pragma unroll
    for (int e = 0; e < 16; ++e) {
        int dim = e * 4 + w;
        int key = t & 63;
        vT[((size_t)bh * DD + dim) * SS + keybase + key] = lds[key][dim];
    }
}

// ---------------------------------------------------------------------------
// Kernel 2 (SELECT): unchanged. Writes per-query take-masks selmask[query][j]
// (u64, bit i = key j*64+i selected). Tie-break identical to prior rounds.
// ---------------------------------------------------------------------------
__global__ __launch_bounds__(256, 4) void select_kernel(
    const float* __restrict__ q,
    const unsigned long long* __restrict__ kbits,
    unsigned long long* __restrict__ selmask)
{
    const int tid  = (int)threadIdx.x;
    const int w    = tid >> 6;
    const int lane = tid & 63;
    const int query = (int)blockIdx.x * QPB + w;
    const int bh    = query >> 10;

    const float qreg = q[(size_t)query * DD + lane];
    const unsigned long long qm = __ballot(qreg > 0.0f);

    const unsigned long long* kb = kbits + (size_t)bh * SS;
    int pbin[16];
    #pragma unroll
    for (int j = 0; j < 16; ++j)
        pbin[j] = (int)__popcll(qm ^ kb[j * 64 + lane]);

    #define COUNT_LE(P, OUTC)                                      \
        { int _c = 0;                                              \
          _Pragma("unroll")                                        \
          for (int j = 0; j < 16; ++j)                             \
              _c += (int)__popcll(__ballot(pbin[j] <= (P)));       \
          (OUTC) = _c; }
    int P = 27, c, clt;
    COUNT_LE(P, c);
    if (c >= KP) {
        COUNT_LE(P - 1, clt);
        while (clt >= KP) { c = clt; --P; COUNT_LE(P - 1, clt); }
    } else {
        do { clt = c; ++P; COUNT_LE(P, c); } while (c < KP);
    }
    const int binP = P;
    const int need = KP - clt;
    #undef COUNT_LE

    unsigned long long* selq = selmask + (size_t)query * 16;
    int tie_base = 0;
    #pragma unroll
    for (int j = 0; j < 16; ++j) {
        bool isGt  = pbin[j] < binP;
        bool isTie = (pbin[j] == binP);
        unsigned long long tiem = __ballot(isTie);
        int rank = tie_base + mbcnt64(tiem);
        bool take = isGt || (isTie && rank < need);
        unsigned long long tm = __ballot(take);
        if (lane == 0) selq[j] = tm;
        tie_base += (int)__popcll(tiem);
    }
}

// ---------------------------------------------------------------------------
// Kernel 3 (ATTN): LDS-staged dense MFMA attention with selection mask.
// 128 thr = 2 waves; wave wq owns q-rows qbase+wq*16..+15 and iterates ALL
// 1024 keys in 16 tiles of 64 (no cross-wave merge). Per tile:
//   stage K-tile (64 keys x 128B) + V^T-tile (64 dims x 128B) via
//   global_load_lds w16 (linear dest, inverse-swizzled source: chunk^=row&7)
//   -> barrier -> QK^T (8 MFMA) -> exp/sel -> P^T in swizzled wave-private
//   LDS -> PV (8 MFMA) -> barrier.
// All ds_read_b128 hit the 8-distinct-chunk pattern = full 32-bank spread.
// Fragment layouts identical to round-4 (verified passing).
// ---------------------------------------------------------------------------
__global__ __launch_bounds__(128, 4) void attn_kernel(
    const float* __restrict__ q, const _Float16* __restrict__ kh,
    const _Float16* __restrict__ vT, const float* __restrict__ mask,
    const unsigned long long* __restrict__ selmask,
    float* __restrict__ out)
{
    const int tid  = (int)threadIdx.x;
    const int wq   = tid >> 6;
    const int lane = tid & 63;
    const int r    = lane & 15;
    const int g    = lane >> 4;
    const int qbase = (int)blockIdx.x * 32;
    const int bh = qbase >> 10;
    const int b  = bh / HH;
    const int query = qbase + wq * 16 + r;
    const int g4 = g * 4;

    __shared__ char sK[8192];        // K tile: 64 keys x 128 B (swizzled)
    __shared__ char sV[8192];        // V^T tile: 64 dims x 128 B (swizzled)
    __shared__ char sP[2][2048];     // per-wave P^T: 16 q x 128 B (swizzled)

    // Q B-frags (scale folded into kh)
    half8v qf[2];
    #pragma unroll
    for (int ks = 0; ks < 2; ++ks) {
        const float* qp = q + (size_t)query * DD + ks * 32 + g * 8;
        float4 f0 = *(const float4*)qp;
        float4 f1 = *(const float4*)(qp + 4);
        half8v h;
        h[0] = (_Float16)f0.x; h[1] = (_Float16)f0.y;
        h[2] = (_Float16)f0.z; h[3] = (_Float16)f0.w;
        h[4] = (_Float16)f1.x; h[5] = (_Float16)f1.y;
        h[6] = (_Float16)f1.z; h[7] = (_Float16)f1.w;
        qf[ks] = h;
    }

    const char* khb = (const char*)(kh + (size_t)bh * SS * DD);   // 128 B/row
    const char* vTb = (const char*)(vT + (size_t)bh * DD * SS);   // 2048 B/row
    const float* maskb = mask + (size_t)b * SS;
    const unsigned long long* selq = selmask + (size_t)query * 16;
    char* sPw = sP[wq];

    f32x4 oacc[4];
    #pragma unroll
    for (int db = 0; db < 4; ++db) oacc[db] = (f32x4){0.f, 0.f, 0.f, 0.f};
    float l_part = 0.0f;

    #pragma unroll 1
    for (int kt = 0; kt < 16; ++kt) {
        // ---- stage tile kt: 512 chunks(16B) each for K and V^T ----
        #pragma unroll
        for (int i = 0; i < 4; ++i) {
            const int c   = i * 128 + tid;          // linear chunk index
            const int row = c >> 3, ch = c & 7;
            const int sch = ch ^ (row & 7);         // inverse swizzle on src
            const void* gK = khb + (((size_t)(kt * 64 + row)) << 7) + (sch << 4);
            const void* gV = vTb + (((size_t)row) << 11) + ((size_t)kt << 7) + (sch << 4);
            char* lK = sK + ((i * 128 + wq * 64) << 4);   // wave-uniform base
            char* lV = sV + ((i * 128 + wq * 64) << 4);
            gl_lds16(gK, lK);
            gl_lds16(gV, lV);
        }
        const unsigned long long smkt = selq[kt];   // covered by barrier drain
        __syncthreads();                             // vmcnt(0) + barrier

        // ---- QK^T: T[key][q], 4 m-tiles x K=64 (2 MFMA each) ----
        f32x4 ct[4];
        #pragma unroll
        for (int mt = 0; mt < 4; ++mt) {
            const int row = mt * 16 + r;            // row&7 == r&7
            half8v ka0 = *(const half8v*)&sK[(row << 7) + ((( g    ) ^ (r & 7)) << 4)];
            half8v ka1 = *(const half8v*)&sK[(row << 7) + (((4 + g) ^ (r & 7)) << 4)];
            f32x4 cc = (f32x4){0.f, 0.f, 0.f, 0.f};
            cc = __builtin_amdgcn_mfma_f32_16x16x32_f16(ka0, qf[0], cc, 0, 0, 0);
            cc = __builtin_amdgcn_mfma_f32_16x16x32_f16(ka1, qf[1], cc, 0, 0, 0);
            ct[mt] = cc;
        }

        // ---- mask + select + exp -> P^T (f16, swizzled) ----
        #pragma unroll
        for (int mt = 0; mt < 4; ++mt) {
            float4 mv = *(const float4*)(maskb + kt * 64 + mt * 16 + g4);
            const unsigned sw = (unsigned)(smkt >> (mt * 16));
            float mvj[4] = {mv.x, mv.y, mv.z, mv.w};
            float e[4];
            #pragma unroll
            for (int j = 0; j < 4; ++j) {
                float s  = ct[mt][j] + mvj[j];
                float ev = __expf(s);
                ev = ((sw >> (g4 + j)) & 1u) ? ev : 0.0f;
                e[j] = ev;
                l_part += ev;
            }
            half2v p0; p0[0] = (_Float16)e[0]; p0[1] = (_Float16)e[1];
            half2v p1; p1[0] = (_Float16)e[2]; p1[1] = (_Float16)e[3];
            char* wp = sPw + (r << 7) + ((((mt * 2) + (g >> 1)) ^ (r & 7)) << 4)
                           + ((g & 1) << 3);
            ((half2v*)wp)[0] = p0;
            ((half2v*)wp)[1] = p1;
        }

        // ---- PV: out^T += V^T_tile . P^T ----
        #pragma unroll
        for (int ks = 0; ks < 2; ++ks) {
            half8v pf = *(const half8v*)&sPw[(r << 7) + (((ks * 4 + g) ^ (r & 7)) << 4)];
            #pragma unroll
            for (int db = 0; db < 4; ++db) {
                const int vrow = db * 16 + r;       // row&7 == r&7
                half8v va = *(const half8v*)&sV[(vrow << 7) + (((ks * 4 + g) ^ (r & 7)) << 4)];
                oacc[db] = __builtin_amdgcn_mfma_f32_16x16x32_f16(va, pf, oacc[db], 0, 0, 0);
            }
        }
        __syncthreads();                             // protect tile buffers
    }

    // ---- finish: l across g-groups; direct store (no cross-wave merge) ----
    l_part += __shfl_xor(l_part, 16);
    l_part += __shfl_xor(l_part, 32);
    const float rinv = __frcp_rn(l_part);
    #pragma unroll
    for (int db = 0; db < 4; ++db) {
        float4 o = make_float4(oacc[db][0] * rinv, oacc[db][1] * rinv,
                               oacc[db][2] * rinv, oacc[db][3] * rinv);
        *(float4*)(out + (size_t)query * DD + db * 16 + g4) = o;
    }
}

extern "C" void kernel_launch(void* const* d_in, const int* in_sizes, int n_in,
                              void* d_out, int out_size, void* d_ws, size_t ws_size,
                              hipStream_t stream) {
    const float* q    = (const float*)d_in[0];
    const float* k    = (const float*)d_in[1];
    const float* v    = (const float*)d_in[2];
    const float* mask = (const float*)d_in[3];
    float* out = (float*)d_out;

    const int rows = BB * HH * SS;                 // 24576
    char* ws = (char*)d_ws;
    unsigned long long* kbits = (unsigned long long*)ws;            // 196608 B
    _Float16* kh = (_Float16*)(ws + (size_t)rows * 8);              // 3145728 B
    _Float16* vT = (_Float16*)(ws + (size_t)rows * 8
                                  + (size_t)rows * DD * 2);         // 3145728 B
    unsigned long long* selmask = (unsigned long long*)(ws + (size_t)rows * 8
                                  + 2 * (size_t)rows * DD * 2);     // 3145728 B

    prep_kernel<<<rows / 64, 256, 0, stream>>>(k, v, kbits, kh, vT);
    select_kernel<<<rows / QPB, 256, 0, stream>>>(q, kbits, selmask);
    attn_kernel<<<rows / 32, 128, 0, stream>>>(q, kh, vT, mask, selmask, out);
}